// Round 6
// baseline (956.389 us; speedup 1.0000x reference)
//
#include <hip/hip_runtime.h>
#include <cstdint>
#include <cstddef>

// Problem constants
#define B_   32
#define L_   1024
#define D_   512
#define M_   (B_ * L_)   // 32768 rows (b*L + l)
#define N8D  4096        // 8*D columns of U
#define SCALEF 1.4142135623730951f
#define LOG2E 1.4426950408889634f

typedef unsigned short u16;
typedef __bf16 bf16x8 __attribute__((ext_vector_type(8)));
typedef unsigned short u16x8 __attribute__((ext_vector_type(8)));
typedef unsigned short u16x4 __attribute__((ext_vector_type(4)));
typedef float f32x4 __attribute__((ext_vector_type(4)));

__device__ __forceinline__ float bf2f(u16 u) {
    union { unsigned int i; float f; } v; v.i = ((unsigned int)u) << 16; return v.f;
}
__device__ __forceinline__ u16 f2bf(float x) {
    union { float f; unsigned int i; } v; v.f = x;
    unsigned int r = (v.i + 0x7fffu + ((v.i >> 16) & 1u)) >> 16;
    return (u16)r;
}
// fast sigmoid: v_exp_f32 + v_rcp_f32 (≈1 ulp f32 — far below bf16 noise)
__device__ __forceinline__ float sigmoid_fast(float z) {
    return __builtin_amdgcn_rcpf(1.0f + __builtin_amdgcn_exp2f(-LOG2E * z));
}

// async global->LDS, 16 bytes per lane. LDS dest = wave-uniform base + lane*16.
__device__ __forceinline__ void gl2lds16(const u16* g, u16* l) {
    __builtin_amdgcn_global_load_lds(
        (const __attribute__((address_space(1))) void*)g,
        (__attribute__((address_space(3))) void*)l, 16, 0, 0);
}

#define VMW(n) asm volatile("s_waitcnt vmcnt(" #n ")" ::: "memory")
#define LGK(n) asm volatile("s_waitcnt lgkmcnt(" #n ")" ::: "memory")
#define SB     __builtin_amdgcn_sched_barrier(0)

// ---------------- f32 -> bf16 convert (seqs), 8 elems/thread ----------------
__global__ __launch_bounds__(256) void f32_to_bf16(const float* __restrict__ in,
                                                   u16* __restrict__ out) {
    size_t i = ((size_t)blockIdx.x * 256 + threadIdx.x) * 8;
    f32x4 v0 = *(const f32x4*)(in + i);
    f32x4 v1 = *(const f32x4*)(in + i + 4);
    u16x8 o;
#pragma unroll
    for (int q = 0; q < 4; ++q) { o[q] = f2bf(v0[q]); o[4 + q] = f2bf(v1[q]); }
    *(u16x8*)(out + i) = o;
}

// ---------------- transpose W (K,4096) f32 -> WT bf16, rows PERMUTED ----------
// Physical WT row p holds logical W column n:  n = dir*2048 + comp*512 + d
//   -> p = dir*2048 + d*4 + comp   (GEMM output columns land scan-interleaved)
__global__ __launch_bounds__(256) void transpose_w(const float* __restrict__ in,
                                                   u16* __restrict__ out,
                                                   int R, int C) {
    __shared__ u16 tile[32][33];
    int bx = blockIdx.x * 32;
    int by = blockIdx.y * 32;
    int tx = threadIdx.x & 31;
    int ty = threadIdx.x >> 5;
#pragma unroll
    for (int i = 0; i < 32; i += 8)
        tile[ty + i][tx] = f2bf(in[(size_t)(by + ty + i) * C + bx + tx]);
    __syncthreads();
#pragma unroll
    for (int i = 0; i < 32; i += 8) {
        int n = bx + ty + i;
        int p = (n >> 11) * 2048 + ((n & 511) << 2) + ((n >> 9) & 3);
        out[(size_t)p * R + by + tx] = tile[tx][ty + i];
    }
}

// ---------------- GEMM 128x256x32 HYBRID: A global->VGPR, B via LDS ---------
// U(M,4096) = A(M,K) * BT(4096,K)^T, all bf16.
// MECHANISM: rounds 1-5 all pinned at MfmaUtil 42% — per-CU phase wall ==
// MFMA-cycles + LDS-port-cycles SUMMED, across 4 schedule variants and even
// 2 independent blocks (r5). Scheduling can't win; so REMOVE LDS traffic:
// the 16x16x32 MFMA A-operand (lane=qm+16*quad -> row qm, k[quad*8..+8)) is
// a direct row-major global pattern -> load A frags global->VGPR (4 x
// dwordx4/wave/phase, reg-double-buffered, L1-served: 8 KiB/phase shared).
// Only B through LDS (4-slot ring x 16 KiB, XOR-swizzled as before).
// Per-CU phase-pair: port 96 KiB (was 144), MFMA 1242 cyc now dominant 1.45x.
// 4 waves 2M x 2N (per-wave 64x128, acc 128 VGPR); 64 KiB LDS -> 2 blocks/CU.
// SYNC LEDGER (1 barrier + 1 VMW per phase; per-wave issue order fixed:
// [4 A-loads(t+1)][4 gl2lds B(t+2)] = 8/phase):
//  RAW B(t): staged t-2; newer = A(t),B(t+1),A(t+1),B(t+2) = 16 -> VMW(12)
//            drains it; barrier(t) broadcasts before slot-t reads.
//  RAW A(t): loaded t-1; newer = B(t+1),A(t+1),B(t+2) = 12 -> VMW(12) exact.
//  WAR slot (t+2)&3: last read at t-2; reads drained at t-2's LGK(0); X's
//            stage(t) is after X crossed barrier(t-1), which requires Y to
//            have ARRIVED at barrier(t-1), i.e. finished reads(t-2). Safe.
//  Peel: VMW(8) at nt-2 (drains B(nt-2),A(nt-2)), VMW(0) at nt-1.
//  Prologue: A(0)+B(0)+B(1) issued, VMW(4) drains A(0),B(0); B(1) in flight.
__global__ __launch_bounds__(256, 2) void gemm_hyb(const u16* __restrict__ A,
                                                   const u16* __restrict__ BT,
                                                   u16* __restrict__ U, int K) {
    __shared__ __align__(16) u16 ldsB[4 * 8192];   // 4 slots x 16 KiB = 64 KiB
    const int t    = threadIdx.x;      // 0..255
    const int lane = t & 63;
    const int wave = t >> 6;           // 0..3
    const int mi   = wave >> 1;        // 0..1 (m half)
    const int ni   = wave & 1;         // 0..1 (n half)
    const int qm   = lane & 15;
    const int quad = lane >> 4;

    // T1: XCD-contiguous block swizzle (4096 blocks, 8 XCDs, bijective)
    const int nwg = gridDim.x;
    const int wg  = blockIdx.x;
    const int swz = (wg & 7) * (nwg >> 3) + (wg >> 3);
    const int bn  = (swz & 15) << 8;   // 16 N-tiles of 256
    const int bm  = (swz >> 4) << 7;   // 256 M-tiles of 128

    // B staging: thread t owns physical bytes [t*16,+16) of each 4 KiB call;
    // logical L0 = P ^ ((P>>3)&0x30) (self-inverse XOR within 64-B rows)
    const int P0   = t * 16;
    const int L0   = P0 ^ ((P0 >> 3) & 0x30);
    const int srow = L0 >> 6;           // 0..63
    const int scol = (L0 & 63) >> 1;    // 0..31 u16, multiple of 8
    const u16* Bg = BT + (size_t)(bn + srow) * K + scol;
    const size_t g64 = (size_t)64 * K;
    u16* ldst = ldsB + t * 8;           // linear dest base

    // B fragment-read lane base (bytes), XOR folded in
    const int fxor = (quad * 16) ^ ((qm & 6) << 3);
    const int bL   = (ni * 128 + qm) * 64 + fxor;   // + nj*1024 per frag
    const char* ldsc = (const char*)ldsB;

    // A direct-global per-lane base: row = bm + mi*64 + qm, k-chunk quad*8
    const u16* pA = A + (size_t)(bm + mi * 64 + qm) * K + quad * 8;
    const size_t aM = (size_t)16 * K;   // m-frag stride (16 rows)

    f32x4 acc[4][8];
#pragma unroll
    for (int i = 0; i < 4; ++i)
#pragma unroll
        for (int j = 0; j < 8; ++j) acc[i][j] = (f32x4)(0.0f);

    bf16x8 a0[4], a1[4];

#define RD16(p) (*(const bf16x8*)(p))

#define LDA(dst, kt) do {                                                    \
        const u16* a_ = pA + (size_t)(kt) * 32;                              \
        dst[0] = RD16(a_);          dst[1] = RD16(a_ + aM);                  \
        dst[2] = RD16(a_ + 2 * aM); dst[3] = RD16(a_ + 3 * aM);              \
    } while (0)

#define STGB(kt, slot) do {                                                  \
        const u16* b_ = Bg + (size_t)(kt) * 32;                              \
        u16* lb = ldst + (slot) * 8192;                                      \
        gl2lds16(b_,           lb);                                          \
        gl2lds16(b_ + g64,     lb + 2048);                                   \
        gl2lds16(b_ + 2 * g64, lb + 4096);                                   \
        gl2lds16(b_ + 3 * g64, lb + 6144);                                   \
    } while (0)

#define GN(j, aC) do {                                                       \
        _Pragma("unroll")                                                    \
        for (int mj = 0; mj < 4; ++mj)                                       \
            acc[mj][j] = __builtin_amdgcn_mfma_f32_16x16x32_bf16(            \
                aC[mj], bbf[j], acc[mj][j], 0, 0, 0);                        \
    } while (0)

// one phase: consume aC + B slot (tt&3); prefetch aN=A(tt+1), stage B(tt+2)
#define PHASE(tt, aC, aN, DO_A, DO_B, VMN) do {                              \
        if (DO_A) { LDA(aN, (tt) + 1); } SB;                                 \
        if (DO_B) { STGB((tt) + 2, ((tt) + 2) & 3); } SB;                    \
        VMW(VMN);                                                            \
        __builtin_amdgcn_s_barrier();                                        \
        const char* Bs_ = ldsc + (((tt) & 3) * 16384);                       \
        bf16x8 bbf[8];                                                       \
        bbf[0] = RD16(Bs_ + bL);        SB;                                  \
        bbf[1] = RD16(Bs_ + bL + 1024); SB;                                  \
        bbf[2] = RD16(Bs_ + bL + 2048); SB;                                  \
        bbf[3] = RD16(Bs_ + bL + 3072); SB;                                  \
        bbf[4] = RD16(Bs_ + bL + 4096); SB;                                  \
        bbf[5] = RD16(Bs_ + bL + 5120); SB;                                  \
        bbf[6] = RD16(Bs_ + bL + 6144); SB;                                  \
        bbf[7] = RD16(Bs_ + bL + 7168); SB;                                  \
        __builtin_amdgcn_s_setprio(1);                                       \
        LGK(7); SB; GN(0, aC); SB;                                           \
        LGK(6); SB; GN(1, aC); SB;                                           \
        LGK(5); SB; GN(2, aC); SB;                                           \
        LGK(4); SB; GN(3, aC); SB;                                           \
        LGK(3); SB; GN(4, aC); SB;                                           \
        LGK(2); SB; GN(5, aC); SB;                                           \
        LGK(1); SB; GN(6, aC); SB;                                           \
        LGK(0); SB; GN(7, aC); SB;                                           \
        __builtin_amdgcn_s_setprio(0);                                       \
    } while (0)

    const int nt = K >> 5;   // 16 (K=512) or 32 (K=1024)

    // prologue: A(0) regs + B(0),B(1) staged; VMW(4) drains A(0),B(0)
    LDA(a0, 0); SB;
    STGB(0, 0); STGB(1, 1); SB;
    VMW(4);

    for (int tt = 0; tt < nt - 2; tt += 2) {
        PHASE(tt,     a0, a1, 1, 1, 12);
        PHASE(tt + 1, a1, a0, 1, 1, 12);
    }
    PHASE(nt - 2, a0, a1, 1, 0, 8);
    PHASE(nt - 1, a1, a0, 0, 0, 0);

#undef PHASE
#undef GN
#undef STGB
#undef LDA
#undef RD16

    // epilogue: C/D layout col=lane&15, row=quad*4+reg
#pragma unroll
    for (int mj = 0; mj < 4; ++mj) {
        const int row0 = bm + mi * 64 + mj * 16 + quad * 4;
#pragma unroll
        for (int nj = 0; nj < 8; ++nj) {
            const int col = bn + ni * 128 + nj * 16 + qm;
#pragma unroll
            for (int r = 0; r < 4; ++r)
                U[(size_t)(row0 + r) * N8D + col] = f2bf(acc[mj][nj][r]);
        }
    }
}

// ---------------- SRU scan: one thread per (b, dir, d) ----------------
// U (interleaved): (b*L+l)*4096 + dir*2048 + d*4 + {0:xt,1:fp,2:rp,3:xp}
// H: (b*L+l)*1024 + dir*512 + d ; C: b*1024 + dir*512 + d
// PF=32 ping-pong prefetch: batch t+1 loads issue BEFORE batch t compute, so
// vmcnt waits for loads never drain the (shared-counter) h-stores.
// Grid 512x64: 32768 threads over all 256 CUs (2 blocks/CU).
template<bool OUT_F32>
__global__ __launch_bounds__(64) void sru_scan(const u16* __restrict__ U,
                                               const float* __restrict__ vf,
                                               const float* __restrict__ vr,
                                               const float* __restrict__ bfv,
                                               const float* __restrict__ brv,
                                               void* __restrict__ Hv,
                                               void* __restrict__ Cv) {
    constexpr int PF = 32;
    constexpr int NB = L_ / PF;  // 32 batches

    int gid = blockIdx.x * blockDim.x + threadIdx.x;  // 0..32767
    int d   = gid & (D_ - 1);
    int dir = (gid >> 9) & 1;   // uniform within a 64-thread block
    int b   = gid >> 10;
    int ch  = dir * D_ + d;

    const float vf_v = vf[ch];
    const float vr_v = vr[ch];
    const float bf_v = bfv[ch];
    const float br_v = brv[ch];

    // direction-adjusted start pointers + signed element steps
    const ptrdiff_t ustep = dir ? -(ptrdiff_t)N8D : (ptrdiff_t)N8D;
    const ptrdiff_t hstep = dir ? -(ptrdiff_t)1024 : (ptrdiff_t)1024;
    const u16* p0 = U + (size_t)b * L_ * N8D + dir * 2048 + d * 4
                      + (dir ? (size_t)(L_ - 1) * N8D : 0);
    const size_t hstart = (size_t)b * L_ * 1024 + ch + (dir ? (size_t)(L_ - 1) * 1024 : 0);
    float* Hf = (float*)Hv + hstart;
    u16*   Hh = (u16*)Hv + hstart;

    float c = 0.0f;

    auto loadB = [&](u16x4 (&buf)[PF], int tb) {
        const u16* base = p0 + (ptrdiff_t)tb * PF * ustep;
#pragma unroll
        for (int i = 0; i < PF; ++i)
            buf[i] = *(const u16x4*)(base + (ptrdiff_t)i * ustep);
    };
    auto compStore = [&](u16x4 (&buf)[PF], int tb) {
        const ptrdiff_t hb = (ptrdiff_t)tb * PF * hstep;
#pragma unroll
        for (int i = 0; i < PF; ++i) {
            float xt = bf2f(buf[i][0]), fp = bf2f(buf[i][1]);
            float rp = bf2f(buf[i][2]), xp = bf2f(buf[i][3]);
            float f = sigmoid_fast(fp + vf_v * c + bf_v);
            float r = sigmoid_fast(rp + vr_v * c + br_v);
            c = f * (c - xt) + xt;                 // f*c + (1-f)*xt
            float xs = xp * SCALEF;
            float h  = r * (c - xs) + xs;          // r*c + (1-r)*xp*SCALE
            ptrdiff_t ho = hb + (ptrdiff_t)i * hstep;
            if (OUT_F32) Hf[ho] = h; else Hh[ho] = f2bf(h);
        }
    };

    u16x4 b0[PF], b1[PF];
    loadB(b0, 0);
    loadB(b1, 1);
    for (int t = 0; t < NB; t += 2) {
        compStore(b0, t);
        if (t + 2 < NB) loadB(b0, t + 2);
        compStore(b1, t + 1);
        if (t + 3 < NB) loadB(b1, t + 3);
    }

    if (OUT_F32) ((float*)Cv)[b * 1024 + ch] = c;
    else         ((u16*)Cv)[b * 1024 + ch]  = f2bf(c);
}

// ---------------- launch ----------------
extern "C" void kernel_launch(void* const* d_in, const int* in_sizes, int n_in,
                              void* d_out, int out_size, void* d_ws, size_t ws_size,
                              hipStream_t stream) {
    (void)in_sizes; (void)n_in; (void)out_size; (void)ws_size;

    const float* seqs = (const float*)d_in[0];
    const float* W0   = (const float*)d_in[1];
    const float* vf0  = (const float*)d_in[2];
    const float* vr0  = (const float*)d_in[3];
    const float* bf0  = (const float*)d_in[4];
    const float* br0  = (const float*)d_in[5];
    const float* W1   = (const float*)d_in[6];
    const float* vf1  = (const float*)d_in[7];
    const float* vr1  = (const float*)d_in[8];
    const float* bf1  = (const float*)d_in[9];
    const float* br1  = (const float*)d_in[10];
    // d_in[11] = lengths : unused by the reference

    float* out = (float*)d_out;  // [c1: 32*1024 f32][out1: 32*1024*1024 f32]
    char* ws = (char*)d_ws;

    const size_t U_BYTES  = (size_t)M_ * N8D * 2;        // 268435456
    const size_t H_BYTES  = (size_t)M_ * 1024 * 2;       // 67108864
    const size_t W0T_B    = (size_t)4096 * 512 * 2;      // 4194304
    const size_t W1T_B    = (size_t)4096 * 1024 * 2;     // 8388608

    u16* U   = (u16*)(ws);
    u16* H0  = (u16*)(ws + U_BYTES);               // also holds seqs_bf16 before scan0
    u16* S16 = H0;                                  // dead after gemm0
    u16* W0T = (u16*)(ws + U_BYTES + H_BYTES);
    u16* W1T = (u16*)(ws + U_BYTES + H_BYTES + W0T_B);
    u16* Cd  = (u16*)(ws + U_BYTES + H_BYTES + W0T_B + W1T_B);  // dummy c, layer 0

    // seqs f32 -> bf16
    f32_to_bf16<<<dim3(M_ * 512 / 8 / 256), 256, 0, stream>>>(seqs, S16);

    // W0 (512,4096) f32 -> W0T bf16 (permuted rows); W1 (1024,4096) -> W1T
    transpose_w<<<dim3(4096 / 32, 512 / 32), 256, 0, stream>>>(W0, W0T, 512, 4096);
    transpose_w<<<dim3(4096 / 32, 1024 / 32), 256, 0, stream>>>(W1, W1T, 1024, 4096);

    // Layer 0: A = seqs_bf16, K=512   (4096 blocks = 256 bm x 16 bn)
    gemm_hyb<<<dim3(4096), 256, 0, stream>>>(S16, W0T, U, 512);
    sru_scan<false><<<dim3(512), 64, 0, stream>>>(U, vf0, vr0, bf0, br0, (void*)H0, (void*)Cd);

    // Layer 1: A = H0 (bf16), K=1024
    gemm_hyb<<<dim3(4096), 256, 0, stream>>>(H0, W1T, U, 1024);
    sru_scan<true><<<dim3(512), 64, 0, stream>>>(U, vf1, vr1, bf1, br1,
                                                 (void*)(out + B_ * 1024), (void*)out);
}